// Round 2
// baseline (617.272 us; speedup 1.0000x reference)
//
#include <hip/hip_runtime.h>
#include <hip/hip_bf16.h>
#include <stdint.h>

// Problem constants (DGRUCell: DIM=512, BATCH=32768)
#define DIM      512
#define TWO_D    1024
#define FIVE_D   2560
#define BATCH    32768
#define LN_EPS   1e-5f
#define GATE_B   0.0f

typedef _Float16 f16x8 __attribute__((ext_vector_type(8)));
typedef _Float16 f16x4 __attribute__((ext_vector_type(4)));
typedef float    f32x4 __attribute__((ext_vector_type(4)));

// ---------------------------------------------------------------------------
// async global->LDS, 16B per lane. LDS dest = wave-uniform base + lane*16.
// ---------------------------------------------------------------------------
__device__ __forceinline__ void async_copy16(const void* g, void* l) {
  __builtin_amdgcn_global_load_lds(
      (const __attribute__((address_space(1))) uint32_t*)g,
      (__attribute__((address_space(3))) uint32_t*)l,
      16, 0, 0);
}

// ---------------------------------------------------------------------------
// K0: fp32 -> fp16 weight conversion (vector of 4 per thread)
// ---------------------------------------------------------------------------
__global__ __launch_bounds__(256)
void cvt_kernel(const float* __restrict__ s, _Float16* __restrict__ d, int n4) {
  int i = blockIdx.x * blockDim.x + threadIdx.x;
  if (i < n4) {
    float4 v = *(const float4*)(s + (size_t)i * 4);
    f16x4 o;
    o[0] = (_Float16)v.x; o[1] = (_Float16)v.y;
    o[2] = (_Float16)v.z; o[3] = (_Float16)v.w;
    *(f16x4*)&d[(size_t)i * 4] = o;
  }
}

// ---------------------------------------------------------------------------
// K1: LN1 over concat(x,h) -> inp fp16 [B, 1024]
// one row per block, 256 threads, 4 elems/thread
// ---------------------------------------------------------------------------
__global__ __launch_bounds__(256)
void ln1_kernel(const float* __restrict__ x, const float* __restrict__ h,
                const float* __restrict__ w, const float* __restrict__ b,
                const float* __restrict__ mask, _Float16* __restrict__ inp)
{
  const int row = blockIdx.x;
  const int t   = threadIdx.x;
  const int col = t * 4;
  const float* src = (col < DIM) ? (x + (size_t)row * DIM + col)
                                 : (h + (size_t)row * DIM + (col - DIM));
  float4 v = *(const float4*)src;
  float s = v.x + v.y + v.z + v.w;
  float q = v.x * v.x + v.y * v.y + v.z * v.z + v.w * v.w;
#pragma unroll
  for (int o = 32; o > 0; o >>= 1) { s += __shfl_xor(s, o); q += __shfl_xor(q, o); }
  __shared__ float red[8];
  const int wid = t >> 6;
  if ((t & 63) == 0) { red[wid] = s; red[4 + wid] = q; }
  __syncthreads();
  s = red[0] + red[1] + red[2] + red[3];
  q = red[4] + red[5] + red[6] + red[7];
  const float mu   = s * (1.0f / TWO_D);
  const float rstd = rsqrtf(q * (1.0f / TWO_D) - mu * mu + LN_EPS);
  float vv[4] = { v.x, v.y, v.z, v.w };
  f16x4 o4;
#pragma unroll
  for (int i = 0; i < 4; ++i)
    o4[i] = (_Float16)(((vv[i] - mu) * rstd * w[col + i] + b[col + i]) * mask[col + i]);
  *(f16x4*)&inp[(size_t)row * TWO_D + col] = o4;
}

// ---------------------------------------------------------------------------
// K3: gate nonlinearities + LN2 -> inp2 fp16; z0/z1 written in-place into the
// gates buffer (positions of g2/g3, read-before-write within the same thread).
// one row per block, 128 threads, j = 4 cols/thread
// ---------------------------------------------------------------------------
__global__ __launch_bounds__(128)
void gate_ln2_kernel(const float* __restrict__ x, const float* __restrict__ h,
                     _Float16* __restrict__ gates,
                     const float* __restrict__ w2, const float* __restrict__ b2,
                     const float* __restrict__ mask, _Float16* __restrict__ inp2)
{
  const int row = blockIdx.x;
  const int t   = threadIdx.x;
  const int j   = t * 4;
  _Float16* g = gates + (size_t)row * FIVE_D;

  f16x4 g0 = *(const f16x4*)&g[j];
  f16x4 g1 = *(const f16x4*)&g[DIM + j];
  f16x4 g2 = *(const f16x4*)&g[2 * DIM + j];
  f16x4 g3 = *(const f16x4*)&g[3 * DIM + j];
  f16x4 g4 = *(const f16x4*)&g[4 * DIM + j];
  float4 xv = *(const float4*)(x + (size_t)row * DIM + j);
  float4 hv = *(const float4*)(h + (size_t)row * DIM + j);
  float xa[4] = { xv.x, xv.y, xv.z, xv.w };
  float ha[4] = { hv.x, hv.y, hv.z, hv.w };

  float xr[4], hr[4];
  f16x4 z0s, z1s;
  float s = 0.f, q = 0.f;
#pragma unroll
  for (int i = 0; i < 4; ++i) {
    float rx = 1.0f / (1.0f + expf(-(float)g0[i]));
    float rh = 1.0f / (1.0f + expf(-(float)g1[i]));
    xr[i] = xa[i] * rx;
    hr[i] = ha[i] * rh;
    float a = (float)g2[i], bb = (float)g3[i], c = (float)g4[i] - GATE_B;
    float m = fmaxf(fmaxf(a, bb), c);
    float e0 = expf(a - m), e1 = expf(bb - m), e2 = expf(c - m);
    float inv = 1.0f / (e0 + e1 + e2);
    z0s[i] = (_Float16)(e0 * inv);
    z1s[i] = (_Float16)(e1 * inv);
    s += xr[i] + hr[i];
    q += xr[i] * xr[i] + hr[i] * hr[i];
  }
  *(f16x4*)&g[2 * DIM + j] = z0s;
  *(f16x4*)&g[3 * DIM + j] = z1s;

#pragma unroll
  for (int o = 32; o > 0; o >>= 1) { s += __shfl_xor(s, o); q += __shfl_xor(q, o); }
  __shared__ float red[4];
  const int wid = t >> 6;
  if ((t & 63) == 0) { red[wid] = s; red[2 + wid] = q; }
  __syncthreads();
  s = red[0] + red[1];
  q = red[2] + red[3];
  const float mu   = s * (1.0f / TWO_D);
  const float rstd = rsqrtf(q * (1.0f / TWO_D) - mu * mu + LN_EPS);

  f16x4 oA, oB;
#pragma unroll
  for (int i = 0; i < 4; ++i) {
    oA[i] = (_Float16)(((xr[i] - mu) * rstd * w2[j + i] + b2[j + i]) * mask[j + i]);
    oB[i] = (_Float16)(((hr[i] - mu) * rstd * w2[DIM + j + i] + b2[DIM + j + i]) * mask[DIM + j + i]);
  }
  *(f16x4*)&inp2[(size_t)row * TWO_D + j]       = oA;
  *(f16x4*)&inp2[(size_t)row * TWO_D + DIM + j] = oB;
}

// ---------------------------------------------------------------------------
// GEMM: C = A[M,K] @ B[N,K]^T (+bias). 128x128 tile, BK=32, 4 waves (2x2),
// each wave 64x64 = 4x4 frags of 16x16, mfma_f32_16x16x32_f16.
//
// LDS layout is FRAGMENT-ORDER (conflict-free): per 16-row segment (1024B),
// byte offset = kchunk*256 + row16*16.  Staging lane l writes seg*1024+l*16
// (global_load_lds linear dest) sourcing global row (l&15), kchunk (l>>4);
// fragment read is then the linear  seg*1024 + lane*16  -> zero bank
// conflicts, and lane l holds the SAME (row,k) elements as a row-major
// layout would give it (row=l&15, k=kt+(l>>4)*8), so MFMA mapping unchanged.
//
// MODE 0: store fp16 gates.  MODE 1: u=tanh(.) then h_new epilogue to fp32.
// ---------------------------------------------------------------------------
template<int MODE>
__global__ __launch_bounds__(256)
void gemm_f16(const _Float16* __restrict__ A,
              const _Float16* __restrict__ Bw,
              const float* __restrict__ bias,
              void* __restrict__ outp,
              const float* __restrict__ X,
              const float* __restrict__ H,
              const _Float16* __restrict__ G,
              int M, int N, int K, int nbx, int total)
{
  __shared__ _Float16 As[128 * 32];
  __shared__ _Float16 Bs[128 * 32];

  // XCD-aware swizzle (total % 8 == 0): each XCD gets a contiguous chunk so
  // consecutive blocks on one XCD share the A row-panel (L2 reuse).
  const int lbid  = blockIdx.x + gridDim.x * blockIdx.y;
  const int chunk = total >> 3;
  const int swz   = (lbid & 7) * chunk + (lbid >> 3);
  const int bxi   = swz % nbx;
  const int byi   = swz / nbx;
  const int brow  = byi * 128;
  const int bcol  = bxi * 128;

  const int tid  = threadIdx.x;
  const int lane = tid & 63;
  const int wid  = tid >> 6;    // 0..3
  const int wr   = wid >> 1;    // wave row 0..1
  const int wc   = wid & 1;     // wave col 0..1
  const int srow = lane & 15;   // staging: global row within segment
  const int kch  = lane >> 4;   // staging: global 16B k-chunk (8 fp16)
  const int fr   = lane & 15;
  const int fq   = lane >> 4;

  f32x4 acc[4][4] = {};

  for (int kt = 0; kt < K; kt += 32) {
#pragma unroll
    for (int c = 0; c < 2; ++c) {
      const int seg = c * 4 + wid;        // 0..7, wave-uniform
      const int r   = seg * 16 + srow;    // global tile row
      async_copy16(A  + (size_t)(brow + r) * K + kt + kch * 8, (char*)As + seg * 1024);
      async_copy16(Bw + (size_t)(bcol + r) * K + kt + kch * 8, (char*)Bs + seg * 1024);
    }
    __syncthreads();

    f16x8 af[4], bf[4];
#pragma unroll
    for (int m = 0; m < 4; ++m)
      af[m] = *(const f16x8*)&As[(wr * 4 + m) * 512 + lane * 8];
#pragma unroll
    for (int n = 0; n < 4; ++n)
      bf[n] = *(const f16x8*)&Bs[(wc * 4 + n) * 512 + lane * 8];
#pragma unroll
    for (int m = 0; m < 4; ++m)
#pragma unroll
      for (int n = 0; n < 4; ++n)
        acc[m][n] = __builtin_amdgcn_mfma_f32_16x16x32_f16(af[m], bf[n], acc[m][n], 0, 0, 0);
    __syncthreads();
  }

  if (MODE == 0) {
    _Float16* Co = (_Float16*)outp;
#pragma unroll
    for (int m = 0; m < 4; ++m) {
#pragma unroll
      for (int n = 0; n < 4; ++n) {
        const int col = bcol + wc * 64 + n * 16 + fr;
        const float bv = bias[col];
#pragma unroll
        for (int jj = 0; jj < 4; ++jj) {
          const int row = brow + wr * 64 + m * 16 + fq * 4 + jj;
          Co[(size_t)row * N + col] = (_Float16)(acc[m][n][jj] + bv);
        }
      }
    }
  } else {
    float* Co = (float*)outp;
#pragma unroll
    for (int m = 0; m < 4; ++m) {
#pragma unroll
      for (int n = 0; n < 4; ++n) {
        const int col = bcol + wc * 64 + n * 16 + fr;
        const float bv = bias[col];
#pragma unroll
        for (int jj = 0; jj < 4; ++jj) {
          const int row = brow + wr * 64 + m * 16 + fq * 4 + jj;
          const float u  = tanhf(acc[m][n][jj] + bv);
          const float z0 = (float)G[(size_t)row * FIVE_D + 2 * DIM + col];
          const float z1 = (float)G[(size_t)row * FIVE_D + 3 * DIM + col];
          const float xv = X[(size_t)row * DIM + col];
          const float hv = H[(size_t)row * DIM + col];
          Co[(size_t)row * DIM + col] = xv * z0 + hv * z1 + u * (1.0f - z0 - z1);
        }
      }
    }
  }
}

// ---------------------------------------------------------------------------
// launch
// ---------------------------------------------------------------------------
extern "C" void kernel_launch(void* const* d_in, const int* in_sizes, int n_in,
                              void* d_out, int out_size, void* d_ws, size_t ws_size,
                              hipStream_t stream)
{
  const float* x    = (const float*)d_in[0];
  const float* h    = (const float*)d_in[1];
  const float* Wg   = (const float*)d_in[2];
  const float* bg   = (const float*)d_in[3];
  const float* Wu   = (const float*)d_in[4];
  const float* bu   = (const float*)d_in[5];
  const float* lnw  = (const float*)d_in[6];
  const float* lnb  = (const float*)d_in[7];
  const float* ln2w = (const float*)d_in[8];
  const float* ln2b = (const float*)d_in[9];
  const float* mask = (const float*)d_in[10];

  // ws layout (bytes):
  //   [0,            5242880)   Wg fp16  [2560*1024]
  //   [5242880,      6291456)   Wu fp16  [512*1024]
  //   [6291456,     73400320)   inp fp16 [32768*1024]   (reused as inp2)
  //   [73400320,   241172480)   gates fp16 [32768*2560] (z0/z1 written in place)
  char* ws = (char*)d_ws;
  _Float16* wg16  = (_Float16*)(ws);
  _Float16* wu16  = (_Float16*)(ws + 5242880);
  _Float16* inp16 = (_Float16*)(ws + 6291456);
  _Float16* gates = (_Float16*)(ws + 73400320);

  cvt_kernel<<<2560, 256, 0, stream>>>(Wg, wg16, FIVE_D * TWO_D / 4);
  cvt_kernel<<<512, 256, 0, stream>>>(Wu, wu16, DIM * TWO_D / 4);

  ln1_kernel<<<BATCH, 256, 0, stream>>>(x, h, lnw, lnb, mask, inp16);

  gemm_f16<0><<<dim3(FIVE_D / 128, BATCH / 128), 256, 0, stream>>>(
      inp16, wg16, bg, (void*)gates, nullptr, nullptr, nullptr,
      BATCH, FIVE_D, TWO_D, FIVE_D / 128, (FIVE_D / 128) * (BATCH / 128));

  gate_ln2_kernel<<<BATCH, 128, 0, stream>>>(x, h, gates, ln2w, ln2b, mask, inp16);

  gemm_f16<1><<<dim3(DIM / 128, BATCH / 128), 256, 0, stream>>>(
      inp16, wu16, bu, d_out, x, h, gates,
      BATCH, DIM, TWO_D, DIM / 128, (DIM / 128) * (BATCH / 128));
}

// Round 3
// 517.857 us; speedup vs baseline: 1.1920x; 1.1920x over previous
//
#include <hip/hip_runtime.h>
#include <hip/hip_bf16.h>
#include <stdint.h>

// Problem constants (DGRUCell: DIM=512, BATCH=32768)
#define DIM      512
#define TWO_D    1024
#define FIVE_D   2560
#define BATCH    32768
#define LN_EPS   1e-5f
#define GATE_B   0.0f

typedef _Float16 f16x8 __attribute__((ext_vector_type(8)));
typedef _Float16 f16x4 __attribute__((ext_vector_type(4)));
typedef float    f32x4 __attribute__((ext_vector_type(4)));

// ---------------------------------------------------------------------------
// async global->LDS, 16B per lane. LDS dest = wave-uniform base + lane*16.
// ---------------------------------------------------------------------------
__device__ __forceinline__ void async_copy16(const void* g, void* l) {
  __builtin_amdgcn_global_load_lds(
      (const __attribute__((address_space(1))) uint32_t*)g,
      (__attribute__((address_space(3))) uint32_t*)l,
      16, 0, 0);
}

// ---------------------------------------------------------------------------
// K0: fp32 -> fp16 weight conversion (vector of 4 per thread)
// ---------------------------------------------------------------------------
__global__ __launch_bounds__(256)
void cvt_kernel(const float* __restrict__ s, _Float16* __restrict__ d, int n4) {
  int i = blockIdx.x * blockDim.x + threadIdx.x;
  if (i < n4) {
    float4 v = *(const float4*)(s + (size_t)i * 4);
    f16x4 o;
    o[0] = (_Float16)v.x; o[1] = (_Float16)v.y;
    o[2] = (_Float16)v.z; o[3] = (_Float16)v.w;
    *(f16x4*)&d[(size_t)i * 4] = o;
  }
}

// ---------------------------------------------------------------------------
// K1: LN1 over concat(x,h) -> inp fp16 [B, 1024]
// one row per block, 256 threads, 4 elems/thread
// ---------------------------------------------------------------------------
__global__ __launch_bounds__(256)
void ln1_kernel(const float* __restrict__ x, const float* __restrict__ h,
                const float* __restrict__ w, const float* __restrict__ b,
                const float* __restrict__ mask, _Float16* __restrict__ inp)
{
  const int row = blockIdx.x;
  const int t   = threadIdx.x;
  const int col = t * 4;
  const float* src = (col < DIM) ? (x + (size_t)row * DIM + col)
                                 : (h + (size_t)row * DIM + (col - DIM));
  float4 v = *(const float4*)src;
  float s = v.x + v.y + v.z + v.w;
  float q = v.x * v.x + v.y * v.y + v.z * v.z + v.w * v.w;
#pragma unroll
  for (int o = 32; o > 0; o >>= 1) { s += __shfl_xor(s, o); q += __shfl_xor(q, o); }
  __shared__ float red[8];
  const int wid = t >> 6;
  if ((t & 63) == 0) { red[wid] = s; red[4 + wid] = q; }
  __syncthreads();
  s = red[0] + red[1] + red[2] + red[3];
  q = red[4] + red[5] + red[6] + red[7];
  const float mu   = s * (1.0f / TWO_D);
  const float rstd = rsqrtf(q * (1.0f / TWO_D) - mu * mu + LN_EPS);
  float vv[4] = { v.x, v.y, v.z, v.w };
  f16x4 o4;
#pragma unroll
  for (int i = 0; i < 4; ++i)
    o4[i] = (_Float16)(((vv[i] - mu) * rstd * w[col + i] + b[col + i]) * mask[col + i]);
  *(f16x4*)&inp[(size_t)row * TWO_D + col] = o4;
}

// ---------------------------------------------------------------------------
// K3: gate nonlinearities + LN2 -> inp2 fp16; z0/z1 written in-place into the
// gates buffer (positions of g2/g3, read-before-write within the same thread).
// one row per block, 128 threads, j = 4 cols/thread
// ---------------------------------------------------------------------------
__global__ __launch_bounds__(128)
void gate_ln2_kernel(const float* __restrict__ x, const float* __restrict__ h,
                     _Float16* __restrict__ gates,
                     const float* __restrict__ w2, const float* __restrict__ b2,
                     const float* __restrict__ mask, _Float16* __restrict__ inp2)
{
  const int row = blockIdx.x;
  const int t   = threadIdx.x;
  const int j   = t * 4;
  _Float16* g = gates + (size_t)row * FIVE_D;

  f16x4 g0 = *(const f16x4*)&g[j];
  f16x4 g1 = *(const f16x4*)&g[DIM + j];
  f16x4 g2 = *(const f16x4*)&g[2 * DIM + j];
  f16x4 g3 = *(const f16x4*)&g[3 * DIM + j];
  f16x4 g4 = *(const f16x4*)&g[4 * DIM + j];
  float4 xv = *(const float4*)(x + (size_t)row * DIM + j);
  float4 hv = *(const float4*)(h + (size_t)row * DIM + j);
  float xa[4] = { xv.x, xv.y, xv.z, xv.w };
  float ha[4] = { hv.x, hv.y, hv.z, hv.w };

  float xr[4], hr[4];
  f16x4 z0s, z1s;
  float s = 0.f, q = 0.f;
#pragma unroll
  for (int i = 0; i < 4; ++i) {
    float rx = 1.0f / (1.0f + expf(-(float)g0[i]));
    float rh = 1.0f / (1.0f + expf(-(float)g1[i]));
    xr[i] = xa[i] * rx;
    hr[i] = ha[i] * rh;
    float a = (float)g2[i], bb = (float)g3[i], c = (float)g4[i] - GATE_B;
    float m = fmaxf(fmaxf(a, bb), c);
    float e0 = expf(a - m), e1 = expf(bb - m), e2 = expf(c - m);
    float inv = 1.0f / (e0 + e1 + e2);
    z0s[i] = (_Float16)(e0 * inv);
    z1s[i] = (_Float16)(e1 * inv);
    s += xr[i] + hr[i];
    q += xr[i] * xr[i] + hr[i] * hr[i];
  }
  *(f16x4*)&g[2 * DIM + j] = z0s;
  *(f16x4*)&g[3 * DIM + j] = z1s;

#pragma unroll
  for (int o = 32; o > 0; o >>= 1) { s += __shfl_xor(s, o); q += __shfl_xor(q, o); }
  __shared__ float red[4];
  const int wid = t >> 6;
  if ((t & 63) == 0) { red[wid] = s; red[2 + wid] = q; }
  __syncthreads();
  s = red[0] + red[1];
  q = red[2] + red[3];
  const float mu   = s * (1.0f / TWO_D);
  const float rstd = rsqrtf(q * (1.0f / TWO_D) - mu * mu + LN_EPS);

  f16x4 oA, oB;
#pragma unroll
  for (int i = 0; i < 4; ++i) {
    oA[i] = (_Float16)(((xr[i] - mu) * rstd * w2[j + i] + b2[j + i]) * mask[j + i]);
    oB[i] = (_Float16)(((hr[i] - mu) * rstd * w2[DIM + j + i] + b2[DIM + j + i]) * mask[DIM + j + i]);
  }
  *(f16x4*)&inp2[(size_t)row * TWO_D + j]       = oA;
  *(f16x4*)&inp2[(size_t)row * TWO_D + DIM + j] = oB;
}

// ---------------------------------------------------------------------------
// GEMM: C = A[M,K] @ B[N,K]^T (+bias). 128x128 tile, BK=32, 4 waves (2x2),
// each wave 64x64 = 4x4 frags of 16x16, mfma_f32_16x16x32_f16.
//
// LDS: row-major-per-segment with an XOR chunk swizzle (rule #21: the SAME
// involution on the staging SOURCE and the ds_read address):
//   staging lane l sources global row (l>>2), 16B-chunk ((l&3) ^ ((l>>3)&3))
//     -> each lane QUAD still reads one contiguous 64B row-slice (16
//        transactions/wave-instr, coalescing preserved),
//   fragment read: byte = row*64 + ((kchunk ^ ((row>>1)&3)) * 16)
//     -> per 16-lane phase start-banks {0,16,4,20,8,24,12,28} x2 = pure
//        2-way bank aliasing, which is free (m136).
//
// MODE 0: store fp16 gates.  MODE 1: u=tanh(.) then h_new epilogue to fp32.
// ---------------------------------------------------------------------------
template<int MODE>
__global__ __launch_bounds__(256)
void gemm_f16(const _Float16* __restrict__ A,
              const _Float16* __restrict__ Bw,
              const float* __restrict__ bias,
              void* __restrict__ outp,
              const float* __restrict__ X,
              const float* __restrict__ H,
              const _Float16* __restrict__ G,
              int M, int N, int K, int nbx, int total)
{
  __shared__ _Float16 As[128 * 32];
  __shared__ _Float16 Bs[128 * 32];

  // XCD-aware swizzle (total % 8 == 0): each XCD gets a contiguous chunk so
  // consecutive blocks on one XCD share the A row-panel (L2 reuse).
  const int lbid  = blockIdx.x + gridDim.x * blockIdx.y;
  const int chunk = total >> 3;
  const int swz   = (lbid & 7) * chunk + (lbid >> 3);
  const int bxi   = swz % nbx;
  const int byi   = swz / nbx;
  const int brow  = byi * 128;
  const int bcol  = bxi * 128;

  const int tid  = threadIdx.x;
  const int lane = tid & 63;
  const int wid  = tid >> 6;    // 0..3
  const int wr   = wid >> 1;    // wave row 0..1
  const int wc   = wid & 1;     // wave col 0..1
  const int srow = lane >> 2;                         // staging row in segment
  const int kch  = (lane & 3) ^ ((lane >> 3) & 3);    // swizzled 16B chunk
  const int fr   = lane & 15;
  const int fq   = lane >> 4;
  const int fsw  = (fq ^ ((fr >> 1) & 3)) * 8;        // swizzled k-offset (elems)

  f32x4 acc[4][4] = {};

  for (int kt = 0; kt < K; kt += 32) {
#pragma unroll
    for (int c = 0; c < 2; ++c) {
      const int seg = c * 4 + wid;        // 0..7, wave-uniform
      const int r   = seg * 16 + srow;    // global tile row
      async_copy16(A  + (size_t)(brow + r) * K + kt + kch * 8, (char*)As + seg * 1024);
      async_copy16(Bw + (size_t)(bcol + r) * K + kt + kch * 8, (char*)Bs + seg * 1024);
    }
    __syncthreads();

    f16x8 af[4], bf[4];
#pragma unroll
    for (int m = 0; m < 4; ++m)
      af[m] = *(const f16x8*)&As[(wr * 64 + m * 16 + fr) * 32 + fsw];
#pragma unroll
    for (int n = 0; n < 4; ++n)
      bf[n] = *(const f16x8*)&Bs[(wc * 64 + n * 16 + fr) * 32 + fsw];
#pragma unroll
    for (int m = 0; m < 4; ++m)
#pragma unroll
      for (int n = 0; n < 4; ++n)
        acc[m][n] = __builtin_amdgcn_mfma_f32_16x16x32_f16(af[m], bf[n], acc[m][n], 0, 0, 0);
    __syncthreads();
  }

  if (MODE == 0) {
    _Float16* Co = (_Float16*)outp;
#pragma unroll
    for (int m = 0; m < 4; ++m) {
#pragma unroll
      for (int n = 0; n < 4; ++n) {
        const int col = bcol + wc * 64 + n * 16 + fr;
        const float bv = bias[col];
#pragma unroll
        for (int jj = 0; jj < 4; ++jj) {
          const int row = brow + wr * 64 + m * 16 + fq * 4 + jj;
          Co[(size_t)row * N + col] = (_Float16)(acc[m][n][jj] + bv);
        }
      }
    }
  } else {
    float* Co = (float*)outp;
#pragma unroll
    for (int m = 0; m < 4; ++m) {
#pragma unroll
      for (int n = 0; n < 4; ++n) {
        const int col = bcol + wc * 64 + n * 16 + fr;
        const float bv = bias[col];
#pragma unroll
        for (int jj = 0; jj < 4; ++jj) {
          const int row = brow + wr * 64 + m * 16 + fq * 4 + jj;
          const float u  = tanhf(acc[m][n][jj] + bv);
          const float z0 = (float)G[(size_t)row * FIVE_D + 2 * DIM + col];
          const float z1 = (float)G[(size_t)row * FIVE_D + 3 * DIM + col];
          const float xv = X[(size_t)row * DIM + col];
          const float hv = H[(size_t)row * DIM + col];
          Co[(size_t)row * DIM + col] = xv * z0 + hv * z1 + u * (1.0f - z0 - z1);
        }
      }
    }
  }
}

// ---------------------------------------------------------------------------
// launch
// ---------------------------------------------------------------------------
extern "C" void kernel_launch(void* const* d_in, const int* in_sizes, int n_in,
                              void* d_out, int out_size, void* d_ws, size_t ws_size,
                              hipStream_t stream)
{
  const float* x    = (const float*)d_in[0];
  const float* h    = (const float*)d_in[1];
  const float* Wg   = (const float*)d_in[2];
  const float* bg   = (const float*)d_in[3];
  const float* Wu   = (const float*)d_in[4];
  const float* bu   = (const float*)d_in[5];
  const float* lnw  = (const float*)d_in[6];
  const float* lnb  = (const float*)d_in[7];
  const float* ln2w = (const float*)d_in[8];
  const float* ln2b = (const float*)d_in[9];
  const float* mask = (const float*)d_in[10];

  // ws layout (bytes):
  //   [0,            5242880)   Wg fp16  [2560*1024]
  //   [5242880,      6291456)   Wu fp16  [512*1024]
  //   [6291456,     73400320)   inp fp16 [32768*1024]   (reused as inp2)
  //   [73400320,   241172480)   gates fp16 [32768*2560] (z0/z1 written in place)
  char* ws = (char*)d_ws;
  _Float16* wg16  = (_Float16*)(ws);
  _Float16* wu16  = (_Float16*)(ws + 5242880);
  _Float16* inp16 = (_Float16*)(ws + 6291456);
  _Float16* gates = (_Float16*)(ws + 73400320);

  cvt_kernel<<<2560, 256, 0, stream>>>(Wg, wg16, FIVE_D * TWO_D / 4);
  cvt_kernel<<<512, 256, 0, stream>>>(Wu, wu16, DIM * TWO_D / 4);

  ln1_kernel<<<BATCH, 256, 0, stream>>>(x, h, lnw, lnb, mask, inp16);

  gemm_f16<0><<<dim3(FIVE_D / 128, BATCH / 128), 256, 0, stream>>>(
      inp16, wg16, bg, (void*)gates, nullptr, nullptr, nullptr,
      BATCH, FIVE_D, TWO_D, FIVE_D / 128, (FIVE_D / 128) * (BATCH / 128));

  gate_ln2_kernel<<<BATCH, 128, 0, stream>>>(x, h, gates, ln2w, ln2b, mask, inp16);

  gemm_f16<1><<<dim3(DIM / 128, BATCH / 128), 256, 0, stream>>>(
      inp16, wu16, bu, d_out, x, h, gates,
      BATCH, DIM, TWO_D, DIM / 128, (DIM / 128) * (BATCH / 128));
}

// Round 4
// 468.159 us; speedup vs baseline: 1.3185x; 1.1062x over previous
//
#include <hip/hip_runtime.h>
#include <hip/hip_bf16.h>
#include <stdint.h>

// Problem constants (DGRUCell: DIM=512, BATCH=32768)
#define DIM      512
#define TWO_D    1024
#define FIVE_D   2560
#define BATCH    32768
#define LN_EPS   1e-5f
#define GATE_B   0.0f

typedef _Float16 f16x8 __attribute__((ext_vector_type(8)));
typedef _Float16 f16x4 __attribute__((ext_vector_type(4)));
typedef float    f32x4 __attribute__((ext_vector_type(4)));

// ---------------------------------------------------------------------------
// async global->LDS, 16B per lane. LDS dest = wave-uniform base + lane*16.
// ---------------------------------------------------------------------------
__device__ __forceinline__ void async_copy16(const void* g, void* l) {
  __builtin_amdgcn_global_load_lds(
      (const __attribute__((address_space(1))) uint32_t*)g,
      (__attribute__((address_space(3))) uint32_t*)l,
      16, 0, 0);
}

// ---------------------------------------------------------------------------
// K0: fp32 -> fp16 weight conversion (vector of 4 per thread)
// ---------------------------------------------------------------------------
__global__ __launch_bounds__(256)
void cvt_kernel(const float* __restrict__ s, _Float16* __restrict__ d, int n4) {
  int i = blockIdx.x * blockDim.x + threadIdx.x;
  if (i < n4) {
    float4 v = *(const float4*)(s + (size_t)i * 4);
    f16x4 o;
    o[0] = (_Float16)v.x; o[1] = (_Float16)v.y;
    o[2] = (_Float16)v.z; o[3] = (_Float16)v.w;
    *(f16x4*)&d[(size_t)i * 4] = o;
  }
}

// ---------------------------------------------------------------------------
// K1: LN1 over concat(x,h) -> inp fp16 [B, 1024]
// one row per block, 256 threads, 4 elems/thread
// ---------------------------------------------------------------------------
__global__ __launch_bounds__(256)
void ln1_kernel(const float* __restrict__ x, const float* __restrict__ h,
                const float* __restrict__ w, const float* __restrict__ b,
                const float* __restrict__ mask, _Float16* __restrict__ inp)
{
  const int row = blockIdx.x;
  const int t   = threadIdx.x;
  const int col = t * 4;
  const float* src = (col < DIM) ? (x + (size_t)row * DIM + col)
                                 : (h + (size_t)row * DIM + (col - DIM));
  float4 v = *(const float4*)src;
  float s = v.x + v.y + v.z + v.w;
  float q = v.x * v.x + v.y * v.y + v.z * v.z + v.w * v.w;
#pragma unroll
  for (int o = 32; o > 0; o >>= 1) { s += __shfl_xor(s, o); q += __shfl_xor(q, o); }
  __shared__ float red[8];
  const int wid = t >> 6;
  if ((t & 63) == 0) { red[wid] = s; red[4 + wid] = q; }
  __syncthreads();
  s = red[0] + red[1] + red[2] + red[3];
  q = red[4] + red[5] + red[6] + red[7];
  const float mu   = s * (1.0f / TWO_D);
  const float rstd = rsqrtf(q * (1.0f / TWO_D) - mu * mu + LN_EPS);
  float vv[4] = { v.x, v.y, v.z, v.w };
  f16x4 o4;
#pragma unroll
  for (int i = 0; i < 4; ++i)
    o4[i] = (_Float16)(((vv[i] - mu) * rstd * w[col + i] + b[col + i]) * mask[col + i]);
  *(f16x4*)&inp[(size_t)row * TWO_D + col] = o4;
}

// ---------------------------------------------------------------------------
// K3: gate nonlinearities + LN2. Writes:
//   inp2 (fp16)            -- LN2 output for GEMM2
//   z2   (fp16, g4 slot)   -- softmax z2, consumed by GEMM2 epilogue
//   part (fp32, d_out)     -- x*z0 + h*z1 partial of h_new
// one row per block, 128 threads, j = 4 cols/thread
// ---------------------------------------------------------------------------
__global__ __launch_bounds__(128)
void gate_ln2_kernel(const float* __restrict__ x, const float* __restrict__ h,
                     _Float16* __restrict__ gates,
                     const float* __restrict__ w2, const float* __restrict__ b2,
                     const float* __restrict__ mask, _Float16* __restrict__ inp2,
                     float* __restrict__ part_out)
{
  const int row = blockIdx.x;
  const int t   = threadIdx.x;
  const int j   = t * 4;
  _Float16* g = gates + (size_t)row * FIVE_D;

  f16x4 g0 = *(const f16x4*)&g[j];
  f16x4 g1 = *(const f16x4*)&g[DIM + j];
  f16x4 g2 = *(const f16x4*)&g[2 * DIM + j];
  f16x4 g3 = *(const f16x4*)&g[3 * DIM + j];
  f16x4 g4 = *(const f16x4*)&g[4 * DIM + j];
  float4 xv = *(const float4*)(x + (size_t)row * DIM + j);
  float4 hv = *(const float4*)(h + (size_t)row * DIM + j);
  float xa[4] = { xv.x, xv.y, xv.z, xv.w };
  float ha[4] = { hv.x, hv.y, hv.z, hv.w };

  float xr[4], hr[4];
  f16x4 z2s;
  float4 part;
  float pa[4];
  float s = 0.f, q = 0.f;
#pragma unroll
  for (int i = 0; i < 4; ++i) {
    float rx = 1.0f / (1.0f + expf(-(float)g0[i]));
    float rh = 1.0f / (1.0f + expf(-(float)g1[i]));
    xr[i] = xa[i] * rx;
    hr[i] = ha[i] * rh;
    float a = (float)g2[i], bb = (float)g3[i], c = (float)g4[i] - GATE_B;
    float m = fmaxf(fmaxf(a, bb), c);
    float e0 = expf(a - m), e1 = expf(bb - m), e2 = expf(c - m);
    float inv = 1.0f / (e0 + e1 + e2);
    float z0 = e0 * inv, z1 = e1 * inv;
    z2s[i] = (_Float16)(e2 * inv);
    pa[i]  = xa[i] * z0 + ha[i] * z1;
    s += xr[i] + hr[i];
    q += xr[i] * xr[i] + hr[i] * hr[i];
  }
  *(f16x4*)&g[4 * DIM + j] = z2s;
  part.x = pa[0]; part.y = pa[1]; part.z = pa[2]; part.w = pa[3];
  *(float4*)&part_out[(size_t)row * DIM + j] = part;

#pragma unroll
  for (int o = 32; o > 0; o >>= 1) { s += __shfl_xor(s, o); q += __shfl_xor(q, o); }
  __shared__ float red[4];
  const int wid = t >> 6;
  if ((t & 63) == 0) { red[wid] = s; red[2 + wid] = q; }
  __syncthreads();
  s = red[0] + red[1];
  q = red[2] + red[3];
  const float mu   = s * (1.0f / TWO_D);
  const float rstd = rsqrtf(q * (1.0f / TWO_D) - mu * mu + LN_EPS);

  f16x4 oA, oB;
#pragma unroll
  for (int i = 0; i < 4; ++i) {
    oA[i] = (_Float16)(((xr[i] - mu) * rstd * w2[j + i] + b2[j + i]) * mask[j + i]);
    oB[i] = (_Float16)(((hr[i] - mu) * rstd * w2[DIM + j + i] + b2[DIM + j + i]) * mask[DIM + j + i]);
  }
  *(f16x4*)&inp2[(size_t)row * TWO_D + j]       = oA;
  *(f16x4*)&inp2[(size_t)row * TWO_D + DIM + j] = oB;
}

// ---------------------------------------------------------------------------
// GEMM: C = A[M,K] @ B[N,K]^T (+bias). 128x128 tile, BK=64, 4 waves (2x2),
// each wave 64x64 = 4x4 frags of 16x16, mfma_f32_16x16x32_f16, 2 k-slices
// per LDS tile (t=0,1).
//
// LDS [128][64] fp16 per matrix (16KB each), XOR chunk swizzle (rule #21 —
// same involution on staging SOURCE and ds_read):
//   slot (r, c) holds global 16B-chunk  c ^ (r&7)  of row r.
//   staging: lane l -> slot byte l*16 in an 8-row segment; sources global
//     row (l>>3), chunk (l&7)^((l>>3)&7)  -> each 8-lane group reads one
//     contiguous (permuted) 128B row-slice: full coalescing.
//   read: chunk (t*4+fq) of row r at byte  r*128 + ((t*4+fq)^(r&7))*16
//     -> per 16-lane phase banks {0,4,...,28} x2 = 2-way aliasing = free.
//
// MODE 0: store fp16 gates.  MODE 1: h_new = part + tanh(.)*z2 -> fp32.
// ---------------------------------------------------------------------------
template<int MODE>
__global__ __launch_bounds__(256)
void gemm_f16(const _Float16* __restrict__ A,
              const _Float16* __restrict__ Bw,
              const float* __restrict__ bias,
              void* __restrict__ outp,
              const _Float16* __restrict__ G,
              int M, int N, int K, int nbx, int total)
{
  __shared__ _Float16 As[128 * 64];
  __shared__ _Float16 Bs[128 * 64];

  // XCD-aware swizzle (total % 8 == 0): each XCD gets a contiguous chunk so
  // consecutive blocks on one XCD share the A row-panel (L2 reuse).
  const int lbid  = blockIdx.x + gridDim.x * blockIdx.y;
  const int chunk = total >> 3;
  const int swz   = (lbid & 7) * chunk + (lbid >> 3);
  const int bxi   = swz % nbx;
  const int byi   = swz / nbx;
  const int brow  = byi * 128;
  const int bcol  = bxi * 128;

  const int tid  = threadIdx.x;
  const int lane = tid & 63;
  const int wid  = tid >> 6;    // 0..3
  const int wr   = wid >> 1;    // wave row 0..1
  const int wc   = wid & 1;     // wave col 0..1
  const int srow = lane >> 3;                       // staging row in 8-row seg
  const int kch  = (lane & 7) ^ ((lane >> 3) & 7);  // swizzled 16B chunk 0..7
  const int fr   = lane & 15;
  const int fq   = lane >> 4;

  f32x4 acc[4][4] = {};

  for (int kt = 0; kt < K; kt += 64) {
#pragma unroll
    for (int c = 0; c < 4; ++c) {
      const int seg = c * 4 + wid;        // 0..15, wave-uniform
      const int r   = seg * 8 + srow;     // global tile row 0..127
      async_copy16(A  + (size_t)(brow + r) * K + kt + kch * 8, (char*)As + seg * 1024);
      async_copy16(Bw + (size_t)(bcol + r) * K + kt + kch * 8, (char*)Bs + seg * 1024);
    }
    __syncthreads();

#pragma unroll
    for (int t = 0; t < 2; ++t) {
      f16x8 af[4], bf[4];
#pragma unroll
      for (int m = 0; m < 4; ++m) {
        const int r = wr * 64 + m * 16 + fr;
        af[m] = *(const f16x8*)&As[r * 64 + (((t * 4 + fq) ^ (r & 7)) * 8)];
      }
#pragma unroll
      for (int n = 0; n < 4; ++n) {
        const int r = wc * 64 + n * 16 + fr;
        bf[n] = *(const f16x8*)&Bs[r * 64 + (((t * 4 + fq) ^ (r & 7)) * 8)];
      }
#pragma unroll
      for (int m = 0; m < 4; ++m)
#pragma unroll
        for (int n = 0; n < 4; ++n)
          acc[m][n] = __builtin_amdgcn_mfma_f32_16x16x32_f16(af[m], bf[n], acc[m][n], 0, 0, 0);
    }
    __syncthreads();
  }

  if (MODE == 0) {
    _Float16* Co = (_Float16*)outp;
#pragma unroll
    for (int m = 0; m < 4; ++m) {
#pragma unroll
      for (int n = 0; n < 4; ++n) {
        const int col = bcol + wc * 64 + n * 16 + fr;
        const float bv = bias[col];
#pragma unroll
        for (int jj = 0; jj < 4; ++jj) {
          const int row = brow + wr * 64 + m * 16 + fq * 4 + jj;
          Co[(size_t)row * N + col] = (_Float16)(acc[m][n][jj] + bv);
        }
      }
    }
  } else {
    float* Co = (float*)outp;
#pragma unroll
    for (int m = 0; m < 4; ++m) {
#pragma unroll
      for (int n = 0; n < 4; ++n) {
        const int col = bcol + wc * 64 + n * 16 + fr;
        const float bv = bias[col];
#pragma unroll
        for (int jj = 0; jj < 4; ++jj) {
          const int row = brow + wr * 64 + m * 16 + fq * 4 + jj;
          const float u  = tanhf(acc[m][n][jj] + bv);
          const float z2 = (float)G[(size_t)row * FIVE_D + 4 * DIM + col];
          const float p  = Co[(size_t)row * DIM + col];   // part from gate_ln2
          Co[(size_t)row * DIM + col] = p + u * z2;
        }
      }
    }
  }
}

// ---------------------------------------------------------------------------
// launch
// ---------------------------------------------------------------------------
extern "C" void kernel_launch(void* const* d_in, const int* in_sizes, int n_in,
                              void* d_out, int out_size, void* d_ws, size_t ws_size,
                              hipStream_t stream)
{
  const float* x    = (const float*)d_in[0];
  const float* h    = (const float*)d_in[1];
  const float* Wg   = (const float*)d_in[2];
  const float* bg   = (const float*)d_in[3];
  const float* Wu   = (const float*)d_in[4];
  const float* bu   = (const float*)d_in[5];
  const float* lnw  = (const float*)d_in[6];
  const float* lnb  = (const float*)d_in[7];
  const float* ln2w = (const float*)d_in[8];
  const float* ln2b = (const float*)d_in[9];
  const float* mask = (const float*)d_in[10];

  // ws layout (bytes):
  //   [0,            5242880)   Wg fp16  [2560*1024]
  //   [5242880,      6291456)   Wu fp16  [512*1024]
  //   [6291456,     73400320)   inp fp16 [32768*1024]   (reused as inp2)
  //   [73400320,   241172480)   gates fp16 [32768*2560] (z2 written into g4)
  char* ws = (char*)d_ws;
  _Float16* wg16  = (_Float16*)(ws);
  _Float16* wu16  = (_Float16*)(ws + 5242880);
  _Float16* inp16 = (_Float16*)(ws + 6291456);
  _Float16* gates = (_Float16*)(ws + 73400320);

  cvt_kernel<<<2560, 256, 0, stream>>>(Wg, wg16, FIVE_D * TWO_D / 4);
  cvt_kernel<<<512, 256, 0, stream>>>(Wu, wu16, DIM * TWO_D / 4);

  ln1_kernel<<<BATCH, 256, 0, stream>>>(x, h, lnw, lnb, mask, inp16);

  gemm_f16<0><<<dim3(FIVE_D / 128, BATCH / 128), 256, 0, stream>>>(
      inp16, wg16, bg, (void*)gates, nullptr,
      BATCH, FIVE_D, TWO_D, FIVE_D / 128, (FIVE_D / 128) * (BATCH / 128));

  gate_ln2_kernel<<<BATCH, 128, 0, stream>>>(x, h, gates, ln2w, ln2b, mask,
                                             inp16, (float*)d_out);

  gemm_f16<1><<<dim3(DIM / 128, BATCH / 128), 256, 0, stream>>>(
      inp16, wu16, bu, d_out, gates,
      BATCH, DIM, TWO_D, DIM / 128, (DIM / 128) * (BATCH / 128));
}

// Round 6
// 429.900 us; speedup vs baseline: 1.4359x; 1.0890x over previous
//
#include <hip/hip_runtime.h>
#include <hip/hip_bf16.h>
#include <stdint.h>

// Problem constants (DGRUCell: DIM=512, BATCH=32768)
#define DIM      512
#define TWO_D    1024
#define FIVE_D   2560
#define BATCH    32768
#define LN_EPS   1e-5f
#define GATE_B   0.0f

typedef _Float16 f16x8 __attribute__((ext_vector_type(8)));
typedef _Float16 f16x4 __attribute__((ext_vector_type(4)));
typedef float    f32x4 __attribute__((ext_vector_type(4)));

// ---------------------------------------------------------------------------
// async global->LDS, 16B per lane. LDS dest = wave-uniform base + lane*16.
// ---------------------------------------------------------------------------
__device__ __forceinline__ void async_copy16(const void* g, void* l) {
  __builtin_amdgcn_global_load_lds(
      (const __attribute__((address_space(1))) uint32_t*)g,
      (__attribute__((address_space(3))) uint32_t*)l,
      16, 0, 0);
}

// Phase drain: every ds_read issued so far must be DATA-COMPLETE before this
// wave may pass the phase-close barrier (another wave may then overwrite the
// region via global_load_lds). asm volatile + memory clobber means loads
// cannot be moved below it; sched_barrier pins it (rule #18).
#define PHASE_DRAIN() do {                                   \
    asm volatile("s_waitcnt lgkmcnt(0)" ::: "memory");       \
    __builtin_amdgcn_sched_barrier(0);                       \
  } while (0)

// ---------------------------------------------------------------------------
// K0: fp32 -> fp16 weight conversion
// ---------------------------------------------------------------------------
__global__ __launch_bounds__(256)
void cvt_kernel(const float* __restrict__ s, _Float16* __restrict__ d, int n4) {
  int i = blockIdx.x * blockDim.x + threadIdx.x;
  if (i < n4) {
    float4 v = *(const float4*)(s + (size_t)i * 4);
    f16x4 o;
    o[0] = (_Float16)v.x; o[1] = (_Float16)v.y;
    o[2] = (_Float16)v.z; o[3] = (_Float16)v.w;
    *(f16x4*)&d[(size_t)i * 4] = o;
  }
}

// ---------------------------------------------------------------------------
// K1: LN1 over concat(x,h) -> inp fp16 [B, 1024]
// ---------------------------------------------------------------------------
__global__ __launch_bounds__(256)
void ln1_kernel(const float* __restrict__ x, const float* __restrict__ h,
                const float* __restrict__ w, const float* __restrict__ b,
                const float* __restrict__ mask, _Float16* __restrict__ inp)
{
  const int row = blockIdx.x;
  const int t   = threadIdx.x;
  const int col = t * 4;
  const float* src = (col < DIM) ? (x + (size_t)row * DIM + col)
                                 : (h + (size_t)row * DIM + (col - DIM));
  float4 v = *(const float4*)src;
  float s = v.x + v.y + v.z + v.w;
  float q = v.x * v.x + v.y * v.y + v.z * v.z + v.w * v.w;
#pragma unroll
  for (int o = 32; o > 0; o >>= 1) { s += __shfl_xor(s, o); q += __shfl_xor(q, o); }
  __shared__ float red[8];
  const int wid = t >> 6;
  if ((t & 63) == 0) { red[wid] = s; red[4 + wid] = q; }
  __syncthreads();
  s = red[0] + red[1] + red[2] + red[3];
  q = red[4] + red[5] + red[6] + red[7];
  const float mu   = s * (1.0f / TWO_D);
  const float rstd = rsqrtf(q * (1.0f / TWO_D) - mu * mu + LN_EPS);
  float vv[4] = { v.x, v.y, v.z, v.w };
  f16x4 o4;
#pragma unroll
  for (int i = 0; i < 4; ++i)
    o4[i] = (_Float16)(((vv[i] - mu) * rstd * w[col + i] + b[col + i]) * mask[col + i]);
  *(f16x4*)&inp[(size_t)row * TWO_D + col] = o4;
}

// ---------------------------------------------------------------------------
// K3: gate nonlinearities + LN2. Writes inp2 (fp16), z2 (fp16, g4 slot),
// part = x*z0 + h*z1 (fp32, d_out).
// ---------------------------------------------------------------------------
__global__ __launch_bounds__(128)
void gate_ln2_kernel(const float* __restrict__ x, const float* __restrict__ h,
                     _Float16* __restrict__ gates,
                     const float* __restrict__ w2, const float* __restrict__ b2,
                     const float* __restrict__ mask, _Float16* __restrict__ inp2,
                     float* __restrict__ part_out)
{
  const int row = blockIdx.x;
  const int t   = threadIdx.x;
  const int j   = t * 4;
  _Float16* g = gates + (size_t)row * FIVE_D;

  f16x4 g0 = *(const f16x4*)&g[j];
  f16x4 g1 = *(const f16x4*)&g[DIM + j];
  f16x4 g2 = *(const f16x4*)&g[2 * DIM + j];
  f16x4 g3 = *(const f16x4*)&g[3 * DIM + j];
  f16x4 g4 = *(const f16x4*)&g[4 * DIM + j];
  float4 xv = *(const float4*)(x + (size_t)row * DIM + j);
  float4 hv = *(const float4*)(h + (size_t)row * DIM + j);
  float xa[4] = { xv.x, xv.y, xv.z, xv.w };
  float ha[4] = { hv.x, hv.y, hv.z, hv.w };

  float xr[4], hr[4];
  f16x4 z2s;
  float4 part;
  float pa[4];
  float s = 0.f, q = 0.f;
#pragma unroll
  for (int i = 0; i < 4; ++i) {
    float rx = 1.0f / (1.0f + expf(-(float)g0[i]));
    float rh = 1.0f / (1.0f + expf(-(float)g1[i]));
    xr[i] = xa[i] * rx;
    hr[i] = ha[i] * rh;
    float a = (float)g2[i], bb = (float)g3[i], c = (float)g4[i] - GATE_B;
    float m = fmaxf(fmaxf(a, bb), c);
    float e0 = expf(a - m), e1 = expf(bb - m), e2 = expf(c - m);
    float inv = 1.0f / (e0 + e1 + e2);
    float z0 = e0 * inv, z1 = e1 * inv;
    z2s[i] = (_Float16)(e2 * inv);
    pa[i]  = xa[i] * z0 + ha[i] * z1;
    s += xr[i] + hr[i];
    q += xr[i] * xr[i] + hr[i] * hr[i];
  }
  *(f16x4*)&g[4 * DIM + j] = z2s;
  part.x = pa[0]; part.y = pa[1]; part.z = pa[2]; part.w = pa[3];
  *(float4*)&part_out[(size_t)row * DIM + j] = part;

#pragma unroll
  for (int o = 32; o > 0; o >>= 1) { s += __shfl_xor(s, o); q += __shfl_xor(q, o); }
  __shared__ float red[4];
  const int wid = t >> 6;
  if ((t & 63) == 0) { red[wid] = s; red[2 + wid] = q; }
  __syncthreads();
  s = red[0] + red[1];
  q = red[2] + red[3];
  const float mu   = s * (1.0f / TWO_D);
  const float rstd = rsqrtf(q * (1.0f / TWO_D) - mu * mu + LN_EPS);

  f16x4 oA, oB;
#pragma unroll
  for (int i = 0; i < 4; ++i) {
    oA[i] = (_Float16)(((xr[i] - mu) * rstd * w2[j + i] + b2[j + i]) * mask[j + i]);
    oB[i] = (_Float16)(((hr[i] - mu) * rstd * w2[DIM + j + i] + b2[DIM + j + i]) * mask[DIM + j + i]);
  }
  *(f16x4*)&inp2[(size_t)row * TWO_D + j]       = oA;
  *(f16x4*)&inp2[(size_t)row * TWO_D + DIM + j] = oB;
}

// ---------------------------------------------------------------------------
// 8-phase 256x256 GEMM: C = A[M,K] @ B[N,K]^T (+bias epilogue per MODE).
// BK=64, 512 threads = 8 waves (2 Mx4 N), per-wave 128x64 output.
// LDS: LA/LB = 2 buffers x 256 x 64 fp16 (64KB each, 128KB total).
// XOR-chunk swizzle (same involution on staging source and ds_read):
//   slot (r,c) holds global chunk c ^ (r&7); read chunk (ks*4+fq)^(r&7)
//   -> 2-way bank aliasing (free). Staging: 8-lane groups read permuted
//   contiguous 128B row slices (coalesced).
// Phase schedule per K-tile t (buf b = t&1):
//   p1: rdA sub0 + rdB sub0 | stage Ah0(t+1)->buf b^1 | 16 MFMA (m0-3,n0-1)
//   p2: rdB sub1            | stage Ah1(t+1)          | 16 MFMA (m0-3,n2-3)
//   p3: rdA sub1            | stage Bh0(t+2)->buf b   | 16 MFMA (m4-7,n2-3)
//   p4: (reg reuse)         | stage Bh1(t+2)          | 16 MFMA (m4-7,n0-1)
// Each phase: reads+stages -> s_barrier -> PHASE_DRAIN (lgkmcnt(0), pinned;
// guarantees this wave's ds_reads are data-complete before it can reach the
// close barrier, after which another wave may overwrite the region) ->
// setprio(1) MFMA setprio(0) -> [p4: counted vmcnt] -> s_barrier.
// vmcnt(4) at tile end = the 2 newest half-tiles (stB(t+2)) stay in flight;
// A(t+1), B(t+1) guaranteed landed. Tail tiles drain with vmcnt(0) (guard-
// skipped loads would break the count).
// ---------------------------------------------------------------------------
template<int MODE>
__global__ __launch_bounds__(512, 2)
void gemm8p(const _Float16* __restrict__ A,
            const _Float16* __restrict__ Bw,
            const float* __restrict__ bias,
            void* __restrict__ outp,
            const _Float16* __restrict__ G,
            int M, int N, int K, int nbx, int total)
{
  __shared__ _Float16 LA[2 * 256 * 64];
  __shared__ _Float16 LB[2 * 256 * 64];

  const int lbid  = blockIdx.x + gridDim.x * blockIdx.y;
  const int chunk = total >> 3;
  const int swz   = (lbid & 7) * chunk + (lbid >> 3);
  const int bxi   = swz % nbx;
  const int byi   = swz / nbx;
  const int brow  = byi * 256;
  const int bcol  = bxi * 256;

  const int tid  = threadIdx.x;
  const int lane = tid & 63;
  const int w    = tid >> 6;      // 0..7
  const int wr   = w >> 2;        // 0..1 (M half)
  const int wc   = w & 3;         // 0..3 (N quarter)
  const int fr   = lane & 15;
  const int fq   = lane >> 4;
  const int gch  = (tid & 7) ^ ((tid >> 3) & 7);  // swizzled source chunk
  const int srw  = tid >> 3;      // staging row 0..63

  const int nt = K >> 6;

  auto stA = [&](int t2, int h) {
    const int b2 = t2 & 1;
    const _Float16* s = A + (size_t)(brow + h * 128 + srw) * K + t2 * 64 + gch * 8;
    char* d = (char*)LA + b2 * 32768 + h * 16384 + tid * 16;
    async_copy16(s, d);
    async_copy16(s + (size_t)64 * K, d + 8192);
  };
  auto stB = [&](int t2, int h) {
    const int b2 = t2 & 1;
    const _Float16* s = Bw + (size_t)(bcol + h * 128 + srw) * K + t2 * 64 + gch * 8;
    char* d = (char*)LB + b2 * 32768 + h * 16384 + tid * 16;
    async_copy16(s, d);
    async_copy16(s + (size_t)64 * K, d + 8192);
  };

  f16x8 af[4][2], bf0[2][2], bf1[2][2];
  f32x4 acc[8][4];
#pragma unroll
  for (int m = 0; m < 8; ++m)
#pragma unroll
    for (int n = 0; n < 4; ++n)
      acc[m][n] = (f32x4){0.f, 0.f, 0.f, 0.f};

  auto rdA = [&](int b, int sub) {
#pragma unroll
    for (int mi = 0; mi < 4; ++mi) {
      const int r = wr * 128 + (sub * 4 + mi) * 16 + fr;
#pragma unroll
      for (int ks = 0; ks < 2; ++ks)
        af[mi][ks] = *(const f16x8*)((const char*)LA + b * 32768 + r * 128 +
                                     (((ks * 4 + fq) ^ (fr & 7)) << 4));
    }
  };
  auto rdB = [&](f16x8 (&bf)[2][2], int b, int sub) {
#pragma unroll
    for (int ni = 0; ni < 2; ++ni) {
      const int r = wc * 64 + (sub * 2 + ni) * 16 + fr;
#pragma unroll
      for (int ks = 0; ks < 2; ++ks)
        bf[ni][ks] = *(const f16x8*)((const char*)LB + b * 32768 + r * 128 +
                                     (((ks * 4 + fq) ^ (fr & 7)) << 4));
    }
  };

  // prologue: tile 0 fully, then B halves of tile 1
  stA(0, 0); stA(0, 1); stB(0, 0); stB(0, 1);
  if (nt > 1) { stB(1, 0); stB(1, 1); }
  if (nt > 1) { asm volatile("s_waitcnt vmcnt(4)" ::: "memory"); }
  else        { asm volatile("s_waitcnt vmcnt(0)" ::: "memory"); }
  __builtin_amdgcn_s_barrier();

  for (int t = 0; t < nt; ++t) {
    const int b = t & 1;
    // ---- p1 -----------------------------------------------------------
    rdA(b, 0);
    rdB(bf0, b, 0);
    if (t + 1 < nt) stA(t + 1, 0);
    __builtin_amdgcn_s_barrier();
    PHASE_DRAIN();
    __builtin_amdgcn_s_setprio(1);
#pragma unroll
    for (int mi = 0; mi < 4; ++mi)
#pragma unroll
      for (int ni = 0; ni < 2; ++ni) {
        acc[mi][ni] = __builtin_amdgcn_mfma_f32_16x16x32_f16(af[mi][0], bf0[ni][0], acc[mi][ni], 0, 0, 0);
        acc[mi][ni] = __builtin_amdgcn_mfma_f32_16x16x32_f16(af[mi][1], bf0[ni][1], acc[mi][ni], 0, 0, 0);
      }
    __builtin_amdgcn_s_setprio(0);
    __builtin_amdgcn_s_barrier();
    // ---- p2 -----------------------------------------------------------
    rdB(bf1, b, 1);
    if (t + 1 < nt) stA(t + 1, 1);
    __builtin_amdgcn_s_barrier();
    PHASE_DRAIN();
    __builtin_amdgcn_s_setprio(1);
#pragma unroll
    for (int mi = 0; mi < 4; ++mi)
#pragma unroll
      for (int ni = 0; ni < 2; ++ni) {
        acc[mi][2 + ni] = __builtin_amdgcn_mfma_f32_16x16x32_f16(af[mi][0], bf1[ni][0], acc[mi][2 + ni], 0, 0, 0);
        acc[mi][2 + ni] = __builtin_amdgcn_mfma_f32_16x16x32_f16(af[mi][1], bf1[ni][1], acc[mi][2 + ni], 0, 0, 0);
      }
    __builtin_amdgcn_s_setprio(0);
    __builtin_amdgcn_s_barrier();
    // ---- p3 -----------------------------------------------------------
    rdA(b, 1);
    if (t + 2 < nt) stB(t + 2, 0);
    __builtin_amdgcn_s_barrier();
    PHASE_DRAIN();
    __builtin_amdgcn_s_setprio(1);
#pragma unroll
    for (int mi = 0; mi < 4; ++mi)
#pragma unroll
      for (int ni = 0; ni < 2; ++ni) {
        acc[4 + mi][2 + ni] = __builtin_amdgcn_mfma_f32_16x16x32_f16(af[mi][0], bf1[ni][0], acc[4 + mi][2 + ni], 0, 0, 0);
        acc[4 + mi][2 + ni] = __builtin_amdgcn_mfma_f32_16x16x32_f16(af[mi][1], bf1[ni][1], acc[4 + mi][2 + ni], 0, 0, 0);
      }
    __builtin_amdgcn_s_setprio(0);
    __builtin_amdgcn_s_barrier();
    // ---- p4 -----------------------------------------------------------
    if (t + 2 < nt) stB(t + 2, 1);
    __builtin_amdgcn_s_barrier();
    PHASE_DRAIN();
    __builtin_amdgcn_s_setprio(1);
#pragma unroll
    for (int mi = 0; mi < 4; ++mi)
#pragma unroll
      for (int ni = 0; ni < 2; ++ni) {
        acc[4 + mi][ni] = __builtin_amdgcn_mfma_f32_16x16x32_f16(af[mi][0], bf0[ni][0], acc[4 + mi][ni], 0, 0, 0);
        acc[4 + mi][ni] = __builtin_amdgcn_mfma_f32_16x16x32_f16(af[mi][1], bf0[ni][1], acc[4 + mi][ni], 0, 0, 0);
      }
    __builtin_amdgcn_s_setprio(0);
    if (t + 2 < nt) { asm volatile("s_waitcnt vmcnt(4)" ::: "memory"); }
    else            { asm volatile("s_waitcnt vmcnt(0)" ::: "memory"); }
    __builtin_amdgcn_s_barrier();
  }

  if (MODE == 0) {
    _Float16* Co = (_Float16*)outp;
#pragma unroll
    for (int m = 0; m < 8; ++m) {
#pragma unroll
      for (int n = 0; n < 4; ++n) {
        const int col = bcol + wc * 64 + n * 16 + fr;
        const float bv = bias[col];
#pragma unroll
        for (int jj = 0; jj < 4; ++jj) {
          const int row = brow + wr * 128 + m * 16 + fq * 4 + jj;
          Co[(size_t)row * N + col] = (_Float16)(acc[m][n][jj] + bv);
        }
      }
    }
  } else {
    float* Co = (float*)outp;
#pragma unroll
    for (int m = 0; m < 8; ++m) {
#pragma unroll
      for (int n = 0; n < 4; ++n) {
        const int col = bcol + wc * 64 + n * 16 + fr;
        const float bv = bias[col];
#pragma unroll
        for (int jj = 0; jj < 4; ++jj) {
          const int row = brow + wr * 128 + m * 16 + fq * 4 + jj;
          const float u  = tanhf(acc[m][n][jj] + bv);
          const float z2 = (float)G[(size_t)row * FIVE_D + 4 * DIM + col];
          const float p  = Co[(size_t)row * DIM + col];   // part from gate_ln2
          Co[(size_t)row * DIM + col] = p + u * z2;
        }
      }
    }
  }
}

// ---------------------------------------------------------------------------
// launch
// ---------------------------------------------------------------------------
extern "C" void kernel_launch(void* const* d_in, const int* in_sizes, int n_in,
                              void* d_out, int out_size, void* d_ws, size_t ws_size,
                              hipStream_t stream)
{
  const float* x    = (const float*)d_in[0];
  const float* h    = (const float*)d_in[1];
  const float* Wg   = (const float*)d_in[2];
  const float* bg   = (const float*)d_in[3];
  const float* Wu   = (const float*)d_in[4];
  const float* bu   = (const float*)d_in[5];
  const float* lnw  = (const float*)d_in[6];
  const float* lnb  = (const float*)d_in[7];
  const float* ln2w = (const float*)d_in[8];
  const float* ln2b = (const float*)d_in[9];
  const float* mask = (const float*)d_in[10];

  // ws layout (bytes):
  //   [0,            5242880)   Wg fp16  [2560*1024]
  //   [5242880,      6291456)   Wu fp16  [512*1024]
  //   [6291456,     73400320)   inp fp16 [32768*1024]   (reused as inp2)
  //   [73400320,   241172480)   gates fp16 [32768*2560] (z2 written into g4)
  char* ws = (char*)d_ws;
  _Float16* wg16  = (_Float16*)(ws);
  _Float16* wu16  = (_Float16*)(ws + 5242880);
  _Float16* inp16 = (_Float16*)(ws + 6291456);
  _Float16* gates = (_Float16*)(ws + 73400320);

  cvt_kernel<<<2560, 256, 0, stream>>>(Wg, wg16, FIVE_D * TWO_D / 4);
  cvt_kernel<<<512, 256, 0, stream>>>(Wu, wu16, DIM * TWO_D / 4);

  ln1_kernel<<<BATCH, 256, 0, stream>>>(x, h, lnw, lnb, mask, inp16);

  gemm8p<0><<<dim3(FIVE_D / 256, BATCH / 256), 512, 0, stream>>>(
      inp16, wg16, bg, (void*)gates, nullptr,
      BATCH, FIVE_D, TWO_D, FIVE_D / 256, (FIVE_D / 256) * (BATCH / 256));

  gate_ln2_kernel<<<BATCH, 128, 0, stream>>>(x, h, gates, ln2w, ln2b, mask,
                                             inp16, (float*)d_out);

  gemm8p<1><<<dim3(DIM / 256, BATCH / 256), 512, 0, stream>>>(
      inp16, wu16, bu, d_out, gates,
      BATCH, DIM, TWO_D, DIM / 256, (DIM / 256) * (BATCH / 256));
}